// Round 13
// baseline (255.233 us; speedup 1.0000x reference)
//
#include <hip/hip_runtime.h>
#include <hip/hip_fp16.h>

#define N_NODES  100000
#define N_RADIAL 16
#define N_CONICAL 16

#define NPB    256                                   // nodes per bucket
#define NBKT   ((N_NODES + NPB - 1) / NPB)           // 391 buckets
#define NBLK_A 500                                   // binfuse scatter blocks (2/CU)
#define BTHR   512                                   // binfuse block threads
#define CHUNK  6400                                  // edges per scatter block (500*6400=3.2M)
#define BINSTRIDE 6400                               // dense block region
#define CAP    10240                                 // compacted bucket cap (mean 8192 + 22σ)
#define NDEG   100096                                // deg array, padded to 256 multiple

typedef _Float16 h2vec __attribute__((ext_vector_type(2)));
static __device__ __forceinline__ float fdot2(__half2 a, __half2 b, float c) {
    h2vec av, bv;
    __builtin_memcpy(&av, &a, 4);
    __builtin_memcpy(&bv, &b, 4);
    return __builtin_amdgcn_fdot2(av, bv, c, false);   // v_dot2_f32_f16
}

// ---------------------------------------------------------------------------
// A. R15/R17/R18/R21-verified in-LDS counting sort (write amp 1.0, edge
//    quads register-cached across passes). R22: scatter blocks also emit
//    one global atomicAdd(&deg[row],1) per edge — rides the idle VMEM pipe
//    (binfuse is latency-bound, <15% busy) and lets agg skip its entire
//    counting pass. deg is hipMemsetAsync-zeroed on-stream beforehand.
//    Block 500: weight re-layouts (fdot2 formats). Blocks 501..: xcon pack.
// ---------------------------------------------------------------------------
__global__ __launch_bounds__(BTHR) void binfuse_kernel(
    const int* __restrict__ idx, const float* __restrict__ x,
    __half2* __restrict__ xcon2,
    const float* __restrict__ W1, const float* __restrict__ W2,
    float* __restrict__ W1tr, __half* __restrict__ W1th, __half* __restrict__ W2th,
    unsigned int* __restrict__ binned, int* __restrict__ cnts,
    int* __restrict__ offs, int* __restrict__ deg, int total, int E) {
    int b = blockIdx.x, tid = threadIdx.x;
    if (b >= NBLK_A) {
        int pb = b - NBLK_A;
        if (pb == 0) {                       // weight re-layouts
            for (int i = tid; i < 2048; i += BTHR) {
                int k = i >> 4, c = i & 15;
                W1tr[k * 16 + c] = W1[c * 128 + k];                       // radial f32
                W1th[k * 16 + c] = __float2half(W1[(16 + c) * 128 + k]); // conical f16
            }
            for (int i = tid; i < 4096; i += BTHR) {
                int kk = i >> 5, o = i & 31;
                W2th[o * 128 + kk] = __float2half(W2[i]);                // W2^T f16
            }
        } else {                             // xcon pack: one float4 -> uint2/thread
            int t = (pb - 1) * BTHR + tid;
            if (t < N_NODES * 4) {
                int n = t >> 2, p = t & 3;
                float4 v = *((const float4*)(x + (size_t)n * 32 + 16) + p);
                __half2 h0 = __floats2half2_rn(v.x, v.y);
                __half2 h1 = __floats2half2_rn(v.z, v.w);
                uint2 st;
                st.x = *(unsigned int*)&h0; st.y = *(unsigned int*)&h1;
                *(uint2*)(xcon2 + 2 * t) = st;
            }
        }
        return;
    }

    __shared__ int cnt[NBKT];
    __shared__ int loff[NBKT];
    __shared__ unsigned int stage[CHUNK];    // 25.6 KB dense staging
    for (int i = tid; i < NBKT; i += BTHR) cnt[i] = 0;
    __syncthreads();

    int lo = b * CHUNK;                      // E/CHUNK = 250 -> block-uniform split
    int cofs = (lo >= E) ? -E : E;
    const int4* rp = (const int4*)(idx + lo);
    const int4* cp = (const int4*)(idx + lo + cofs);
    const int nq = CHUNK >> 2;               // 1600 quads

    // pass 1: load+cache quads; LDS bucket counts + GLOBAL per-node degree
    int4 rr[4], cc[4];
    #pragma unroll
    for (int u = 0; u < 4; u++) {
        int q = tid + u * BTHR;
        if (q < nq) {
            rr[u] = rp[q];
            cc[u] = cp[q];
            atomicAdd(&cnt[rr[u].x >> 8], 1);
            atomicAdd(&cnt[rr[u].y >> 8], 1);
            atomicAdd(&cnt[rr[u].z >> 8], 1);
            atomicAdd(&cnt[rr[u].w >> 8], 1);
            atomicAdd(&deg[rr[u].x], 1);
            atomicAdd(&deg[rr[u].y], 1);
            atomicAdd(&deg[rr[u].z], 1);
            atomicAdd(&deg[rr[u].w], 1);
        }
    }
    __syncthreads();

    // pass 2: exclusive scan over 391 buckets by wave 0 (7 buckets/lane)
    if (tid < 64) {
        int c[7]; int s = 0;
        #pragma unroll
        for (int u = 0; u < 7; u++) {
            int i = tid * 7 + u;
            c[u] = (i < NBKT) ? cnt[i] : 0;
            s += c[u];
        }
        int t = s;
        #pragma unroll
        for (int off = 1; off < 64; off <<= 1) {
            int u = __shfl_up(t, off, 64);
            if (tid >= off) t += u;
        }
        int ex = t - s;
        #pragma unroll
        for (int u = 0; u < 7; u++) {
            int i = tid * 7 + u;
            if (i < NBKT) { loff[i] = ex; ex += c[u]; }
        }
    }
    __syncthreads();

    // publish exact lengths + starts for agg
    for (int i = tid; i < NBKT; i += BTHR) {
        cnts[i * NBLK_A + b] = cnt[i];
        offs[i * NBLK_A + b] = loff[i];
    }
    __syncthreads();                         // loff reads done before cursor use

    // pass 3: scatter into dense LDS stage from the register cache
    #pragma unroll
    for (int u = 0; u < 4; u++) {
        int q = tid + u * BTHR;
        if (q < nq) {
            int4 r = rr[u];
            int4 c = cc[u];
            int p0 = atomicAdd(&loff[r.x >> 8], 1);
            int p1 = atomicAdd(&loff[r.y >> 8], 1);
            int p2 = atomicAdd(&loff[r.z >> 8], 1);
            int p3 = atomicAdd(&loff[r.w >> 8], 1);
            stage[p0] = ((unsigned int)(r.x & 255) << 17) | (unsigned int)c.x;
            stage[p1] = ((unsigned int)(r.y & 255) << 17) | (unsigned int)c.y;
            stage[p2] = ((unsigned int)(r.z & 255) << 17) | (unsigned int)c.z;
            stage[p3] = ((unsigned int)(r.w & 255) << 17) | (unsigned int)c.w;
        }
    }
    __syncthreads();

    // pass 4: coalesced full-line flush (write amp 1.0)
    unsigned int* dst = binned + (size_t)b * BINSTRIDE;
    for (int i = tid; i < CHUNK; i += BTHR) dst[i] = stage[i];
}

// ---------------------------------------------------------------------------
// B. Bucket accumulate, R22: NO counting pass. Wave 0 loads the bucket's
//    256 precomputed degrees (coalesced int4), shuffle-scans them into
//    soff; the single remaining edge pass loads each lane's contiguous
//    sub-run half (3 unconditional uint4, R21) and scatters into sedge.
//    Pass 4 accumulates in f16 via v_pk_add_f16 (4 instr per 16B gather,
//    was 8 cvt + 8 add); deg-division epilogue stays f32.
// ---------------------------------------------------------------------------
__global__ __launch_bounds__(1024, 2) void agg_kernel(
    const __half* __restrict__ xcon, const int* __restrict__ cnts,
    const int* __restrict__ offs,
    const unsigned int* __restrict__ binned,
    const int* __restrict__ deg, __half* __restrict__ agg) {
    __shared__ unsigned int sedge[CAP];   // 40 KB
    __shared__ int scnt[NPB];
    __shared__ int soff[NPB];
    int orig = blockIdx.x;
    int xcd = orig & 7, i8 = orig >> 3;
    const int qq = NBKT >> 3, rr = NBKT & 7;
    int b = (xcd < rr) ? xcd * (qq + 1) + i8
                       : rr * (qq + 1) + (xcd - rr) * qq + i8;
    int tid = threadIdx.x;

    // scan: wave 0 loads deg slice (padded to zero past N_NODES) + scans
    if (tid < 64) {
        int i0 = tid * 4;
        int4 d4 = *(const int4*)(deg + b * NPB + i0);
        scnt[i0]     = d4.x;
        scnt[i0 + 1] = d4.y;
        scnt[i0 + 2] = d4.z;
        scnt[i0 + 3] = d4.w;
        int s = d4.x + d4.y + d4.z + d4.w;
        int t = s;
        #pragma unroll
        for (int off = 1; off < 64; off <<= 1) {
            int u = __shfl_up(t, off, 64);
            if (tid >= off) t += u;
        }
        int ex = t - s;
        soff[i0]     = ex;
        soff[i0 + 1] = ex + d4.x;
        soff[i0 + 2] = ex + d4.x + d4.y;
        soff[i0 + 3] = ex + d4.x + d4.y + d4.z;
    }
    __syncthreads();

    // edge pass: load contiguous half (R21) + scatter into node-sorted sedge
    int sub = tid >> 1, l = tid & 1;      // 500 sub-runs, 2 lanes each
    int sc = 0; unsigned int base = 0;
    if (sub < NBLK_A) {
        sc   = cnts[b * NBLK_A + sub];
        base = (unsigned int)sub * BINSTRIDE
             + (unsigned int)offs[b * NBLK_A + sub];
    }
    int j0 = l ? (sc >> 1) : 0;           // contiguous half per lane
    int j1 = l ? sc : (sc >> 1);

    unsigned int ev[12];
    {
        const uint4* vp = (const uint4*)(binned + base + j0);   // 4B-aligned ok
        uint4 v0 = vp[0], v1 = vp[1], v2 = vp[2];
        ev[0]=v0.x; ev[1]=v0.y; ev[2]=v0.z;  ev[3]=v0.w;
        ev[4]=v1.x; ev[5]=v1.y; ev[6]=v1.z;  ev[7]=v1.w;
        ev[8]=v2.x; ev[9]=v2.y; ev[10]=v2.z; ev[11]=v2.w;
    }
    #pragma unroll
    for (int u = 0; u < 12; u++) {
        if (j0 + u < j1) {
            unsigned int p = ev[u];
            int pos = atomicAdd(&soff[p >> 17], 1);
            sedge[pos] = p & 0x1FFFFu;
        }
    }
    for (int j = j0 + 12; j < j1; j++) {
        unsigned int p = binned[base + j];
        int pos = atomicAdd(&soff[p >> 17], 1);
        sedge[pos] = p & 0x1FFFFu;
    }
    __syncthreads();

    // pass 4: accumulate in f16 (v_pk_add_f16), 2 lanes/node, 16B gathers
    if (tid < 2 * NPB) {
        int nl = tid >> 1, q = tid & 1;
        int c  = scnt[nl];
        int s0 = soff[nl] - c;                 // soff advanced to row end
        __half2 z = __floats2half2_rn(0.f, 0.f);
        __half2 ah0 = z, ah1 = z, ah2 = z, ah3 = z;
        #pragma unroll 2
        for (int k = 0; k < c; k++) {
            int col = (int)sedge[s0 + k];      // broadcast within pair
            uint4 raw = ((const uint4*)(xcon + (size_t)col * 16))[q];
            ah0 = __hadd2(ah0, *(const __half2*)&raw.x);
            ah1 = __hadd2(ah1, *(const __half2*)&raw.y);
            ah2 = __hadd2(ah2, *(const __half2*)&raw.z);
            ah3 = __hadd2(ah3, *(const __half2*)&raw.w);
        }
        int n = b * NPB + nl;
        if (n < N_NODES) {
            float inv = 1.0f / (float)max(c, 1);
            float2 f0 = __half22float2(ah0);
            float2 f1 = __half22float2(ah1);
            float2 f2 = __half22float2(ah2);
            float2 f3 = __half22float2(ah3);
            __half2 h0 = __floats2half2_rn(f0.x * inv, f0.y * inv);
            __half2 h1 = __floats2half2_rn(f1.x * inv, f1.y * inv);
            __half2 h2 = __floats2half2_rn(f2.x * inv, f2.y * inv);
            __half2 h3 = __floats2half2_rn(f3.x * inv, f3.y * inv);
            uint4 st;
            st.x = *(unsigned int*)&h0; st.y = *(unsigned int*)&h1;
            st.z = *(unsigned int*)&h2; st.w = *(unsigned int*)&h3;
            *(uint4*)(agg + (size_t)n * 16 + q * 8) = st;   // 16B/lane
        }
    }
}

// ---------------------------------------------------------------------------
// C. MLP (R18-verified fdot2 path, byte-identical). Phase A: radial f32 FMA
//    + conical fdot2 on agg's native half2; phase B: H2 half2 via fdot2
//    against f16 W2^T; f32 accumulation. 8 waves / 64-node tile,
//    wave-uniform weight rows on the scalar pipe.
// ---------------------------------------------------------------------------
__global__ __launch_bounds__(512, 4) void mlp_kernel(
    const float* __restrict__ x, const __half* __restrict__ agg,
    const float* __restrict__ W1tr, const __half* __restrict__ W1th,
    const float* __restrict__ b1,
    const __half* __restrict__ W2th, const float* __restrict__ b2,
    float* __restrict__ out, int N) {
    __shared__ __half2 H2[64 * 64];   // [kp][node], 16 KB
    int tid  = threadIdx.x;
    int lane = tid & 63;
    int ws   = __builtin_amdgcn_readfirstlane(tid >> 6);
    int n    = blockIdx.x * 64 + lane;
    int nc   = min(n, N - 1);

    float combr[16];
    const float4* xr = (const float4*)(x + (size_t)nc * 32);
    #pragma unroll
    for (int c = 0; c < 4; c++) {
        float4 v = xr[c];
        combr[c*4+0] = v.x; combr[c*4+1] = v.y;
        combr[c*4+2] = v.z; combr[c*4+3] = v.w;
    }
    __half2 aggh[8];
    const __half2* ar = (const __half2*)(agg + (size_t)nc * 16);
    #pragma unroll
    for (int c = 0; c < 8; c++) aggh[c] = ar[c];

    #pragma unroll
    for (int i = 0; i < 16; i += 2) {
        int k0 = ws * 16 + i;
        const float*   w1a  = W1tr + k0 * 16;
        const float*   w1b  = w1a + 16;
        const __half2* w1ha = (const __half2*)(W1th + k0 * 16);
        const __half2* w1hb = w1ha + 8;
        float ha = b1[k0], hb = b1[k0 + 1];
        #pragma unroll
        for (int c = 0; c < 16; c++) {
            ha = fmaf(combr[c], w1a[c], ha);
            hb = fmaf(combr[c], w1b[c], hb);
        }
        #pragma unroll
        for (int p = 0; p < 8; p++) {
            ha = fdot2(aggh[p], w1ha[p], ha);
            hb = fdot2(aggh[p], w1hb[p], hb);
        }
        ha = fmaxf(ha, 0.f); hb = fmaxf(hb, 0.f);
        H2[(k0 >> 1) * 64 + lane] = __floats2half2_rn(ha, hb);
    }
    __syncthreads();

    int o0 = ws * 4;
    const __half2* w20 = (const __half2*)(W2th + (o0 + 0) * 128);
    const __half2* w21 = (const __half2*)(W2th + (o0 + 1) * 128);
    const __half2* w22 = (const __half2*)(W2th + (o0 + 2) * 128);
    const __half2* w23 = (const __half2*)(W2th + (o0 + 3) * 128);
    float acc0 = b2[o0+0], acc1 = b2[o0+1], acc2 = b2[o0+2], acc3 = b2[o0+3];
    #pragma unroll 8
    for (int kp = 0; kp < 64; kp++) {
        __half2 hq = H2[kp * 64 + lane];
        acc0 = fdot2(hq, w20[kp], acc0);
        acc1 = fdot2(hq, w21[kp], acc1);
        acc2 = fdot2(hq, w22[kp], acc2);
        acc3 = fdot2(hq, w23[kp], acc3);
    }
    if (n < N) {
        float* op = out + (size_t)n * 32 + o0;
        op[0] = acc0; op[1] = acc1; op[2] = acc2; op[3] = acc3;
    }
}

extern "C" void kernel_launch(void* const* d_in, const int* in_sizes, int n_in,
                              void* d_out, int out_size, void* d_ws, size_t ws_size,
                              hipStream_t stream) {
    const float* x   = (const float*)d_in[0];
    const int*   idx = (const int*)d_in[1];
    const float* W1  = (const float*)d_in[2];
    const float* b1  = (const float*)d_in[3];
    const float* W2  = (const float*)d_in[4];
    const float* b2  = (const float*)d_in[5];
    float* out = (float*)d_out;

    const int E = in_sizes[1] / 2;     // 1,600,000
    const int total = 2 * E;           // 3,200,000

    // ws layout (~21.5 MB):
    //   agg 3.2MB | xcon 3.2MB | W1tr 8KB | W1th 4KB | W2th 8KB |
    //   deg 400KB (padded, memset-zeroed) | cnts 782KB | offs 782KB |
    //   binned 500*6400*4 = 12.8MB
    char* base = (char*)d_ws;
    __half*       agg    = (__half*)base;                    // 3,203,072
    __half*       xcon   = (__half*)(base + 3203072);        // 3,203,072
    float*        W1tr   = (float*)(base + 6406144);         // 8,192
    __half*       W1th   = (__half*)(base + 6414336);        // 4,096
    __half*       W2th   = (__half*)(base + 6418432);        // 8,192
    int*          deg    = (int*)(base + 6426624);           // 400,384
    int*          cnts   = (int*)(base + 6827008);           // 782,336
    int*          offs   = (int*)(base + 7609344);           // 782,336
    unsigned int* binned = (unsigned int*)(base + 8391680);  // 12.8 MB

    hipMemsetAsync(deg, 0, NDEG * sizeof(int), stream);      // capture-safe

    int pack_blocks = (N_NODES * 4 + BTHR - 1) / BTHR;   // 782
    binfuse_kernel<<<NBLK_A + 1 + pack_blocks, BTHR, 0, stream>>>(
        idx, x, (__half2*)xcon, W1, W2, W1tr, W1th, W2th,
        binned, cnts, offs, deg, total, E);
    agg_kernel<<<NBKT, 1024, 0, stream>>>(xcon, cnts, offs, binned, deg, agg);
    mlp_kernel<<<(N_NODES + 63) / 64, 512, 0, stream>>>(
        x, agg, W1tr, W1th, b1, W2th, b2, out, N_NODES);
}

// Round 14
// 132.013 us; speedup vs baseline: 1.9334x; 1.9334x over previous
//
#include <hip/hip_runtime.h>
#include <hip/hip_fp16.h>

#define N_NODES  100000
#define N_RADIAL 16
#define N_CONICAL 16

#define NPB    256                                   // nodes per bucket
#define NBKT   ((N_NODES + NPB - 1) / NPB)           // 391 buckets
#define NBLK_A 500                                   // binfuse scatter blocks (2/CU)
#define BTHR   512                                   // binfuse block threads
#define CHUNK  6400                                  // edges per scatter block (500*6400=3.2M)
#define BINSTRIDE 6400                               // dense block region
#define CAP    10240                                 // compacted bucket cap (mean 8192 + 22σ)

typedef _Float16 h2vec __attribute__((ext_vector_type(2)));
static __device__ __forceinline__ float fdot2(__half2 a, __half2 b, float c) {
    h2vec av, bv;
    __builtin_memcpy(&av, &a, 4);
    __builtin_memcpy(&bv, &b, 4);
    return __builtin_amdgcn_fdot2(av, bv, c, false);   // v_dot2_f32_f16
}

// ---------------------------------------------------------------------------
// A. R21-verified (byte-identical): in-LDS counting sort, write amp 1.0,
//    edge quads register-cached across passes (idx read exactly once;
//    pass 3 = pure atomic->LDS store). R22's global deg atomics REVERTED:
//    3.2M scattered atomics cost 128MB writeback + atomic-pipe serialization
//    (WRITE_SIZE law applies to atomics too).
//    Block 500: weight re-layouts (fdot2 formats). Blocks 501..: xcon pack.
// ---------------------------------------------------------------------------
__global__ __launch_bounds__(BTHR) void binfuse_kernel(
    const int* __restrict__ idx, const float* __restrict__ x,
    __half2* __restrict__ xcon2,
    const float* __restrict__ W1, const float* __restrict__ W2,
    float* __restrict__ W1tr, __half* __restrict__ W1th, __half* __restrict__ W2th,
    unsigned int* __restrict__ binned, int* __restrict__ cnts,
    int* __restrict__ offs, int total, int E) {
    int b = blockIdx.x, tid = threadIdx.x;
    if (b >= NBLK_A) {
        int pb = b - NBLK_A;
        if (pb == 0) {                       // weight re-layouts
            for (int i = tid; i < 2048; i += BTHR) {
                int k = i >> 4, c = i & 15;
                W1tr[k * 16 + c] = W1[c * 128 + k];                       // radial f32
                W1th[k * 16 + c] = __float2half(W1[(16 + c) * 128 + k]); // conical f16
            }
            for (int i = tid; i < 4096; i += BTHR) {
                int kk = i >> 5, o = i & 31;
                W2th[o * 128 + kk] = __float2half(W2[i]);                // W2^T f16
            }
        } else {                             // xcon pack: one float4 -> uint2/thread
            int t = (pb - 1) * BTHR + tid;
            if (t < N_NODES * 4) {
                int n = t >> 2, p = t & 3;
                float4 v = *((const float4*)(x + (size_t)n * 32 + 16) + p);
                __half2 h0 = __floats2half2_rn(v.x, v.y);
                __half2 h1 = __floats2half2_rn(v.z, v.w);
                uint2 st;
                st.x = *(unsigned int*)&h0; st.y = *(unsigned int*)&h1;
                *(uint2*)(xcon2 + 2 * t) = st;
            }
        }
        return;
    }

    __shared__ int cnt[NBKT];
    __shared__ int loff[NBKT];
    __shared__ unsigned int stage[CHUNK];    // 25.6 KB dense staging
    for (int i = tid; i < NBKT; i += BTHR) cnt[i] = 0;
    __syncthreads();

    int lo = b * CHUNK;                      // E/CHUNK = 250 -> block-uniform split
    int cofs = (lo >= E) ? -E : E;
    const int4* rp = (const int4*)(idx + lo);
    const int4* cp = (const int4*)(idx + lo + cofs);
    const int nq = CHUNK >> 2;               // 1600 quads

    // pass 1: load+cache quads, per-bucket counts (idx read exactly once)
    int4 rr[4], cc[4];
    #pragma unroll
    for (int u = 0; u < 4; u++) {
        int q = tid + u * BTHR;
        if (q < nq) {
            rr[u] = rp[q];
            cc[u] = cp[q];
            atomicAdd(&cnt[rr[u].x >> 8], 1);
            atomicAdd(&cnt[rr[u].y >> 8], 1);
            atomicAdd(&cnt[rr[u].z >> 8], 1);
            atomicAdd(&cnt[rr[u].w >> 8], 1);
        }
    }
    __syncthreads();

    // pass 2: exclusive scan over 391 buckets by wave 0 (7 buckets/lane)
    if (tid < 64) {
        int c[7]; int s = 0;
        #pragma unroll
        for (int u = 0; u < 7; u++) {
            int i = tid * 7 + u;
            c[u] = (i < NBKT) ? cnt[i] : 0;
            s += c[u];
        }
        int t = s;
        #pragma unroll
        for (int off = 1; off < 64; off <<= 1) {
            int u = __shfl_up(t, off, 64);
            if (tid >= off) t += u;
        }
        int ex = t - s;
        #pragma unroll
        for (int u = 0; u < 7; u++) {
            int i = tid * 7 + u;
            if (i < NBKT) { loff[i] = ex; ex += c[u]; }
        }
    }
    __syncthreads();

    // publish exact lengths + starts for agg
    for (int i = tid; i < NBKT; i += BTHR) {
        cnts[i * NBLK_A + b] = cnt[i];
        offs[i * NBLK_A + b] = loff[i];
    }
    __syncthreads();                         // loff reads done before cursor use

    // pass 3: scatter into dense LDS stage from the register cache
    #pragma unroll
    for (int u = 0; u < 4; u++) {
        int q = tid + u * BTHR;
        if (q < nq) {
            int4 r = rr[u];
            int4 c = cc[u];
            int p0 = atomicAdd(&loff[r.x >> 8], 1);
            int p1 = atomicAdd(&loff[r.y >> 8], 1);
            int p2 = atomicAdd(&loff[r.z >> 8], 1);
            int p3 = atomicAdd(&loff[r.w >> 8], 1);
            stage[p0] = ((unsigned int)(r.x & 255) << 17) | (unsigned int)c.x;
            stage[p1] = ((unsigned int)(r.y & 255) << 17) | (unsigned int)c.y;
            stage[p2] = ((unsigned int)(r.z & 255) << 17) | (unsigned int)c.z;
            stage[p3] = ((unsigned int)(r.w & 255) << 17) | (unsigned int)c.w;
        }
    }
    __syncthreads();

    // pass 4: coalesced full-line flush (write amp 1.0)
    unsigned int* dst = binned + (size_t)b * BINSTRIDE;
    for (int i = tid; i < CHUNK; i += BTHR) dst[i] = stage[i];
}

// ---------------------------------------------------------------------------
// B. Bucket accumulate (R21-verified structure: contiguous-half register
//    cache, 3 unconditional uint4 loads, predicated atomics, single-wave
//    scan, bijective XCD swizzle). R23: pass 4 accumulates in f16 via
//    v_pk_add_f16 (4 instr per 16B gather, was 8 cvt + 8 f32 add) —
//    correctness-verified in R22 (absmax unchanged 0.0078125); f32
//    deg-division epilogue.
// ---------------------------------------------------------------------------
__global__ __launch_bounds__(1024, 2) void agg_kernel(
    const __half* __restrict__ xcon, const int* __restrict__ cnts,
    const int* __restrict__ offs,
    const unsigned int* __restrict__ binned, __half* __restrict__ agg) {
    __shared__ unsigned int sedge[CAP];   // 40 KB
    __shared__ int scnt[NPB];
    __shared__ int soff[NPB];
    int orig = blockIdx.x;
    int xcd = orig & 7, i8 = orig >> 3;
    const int qq = NBKT >> 3, rr = NBKT & 7;
    int b = (xcd < rr) ? xcd * (qq + 1) + i8
                       : rr * (qq + 1) + (xcd - rr) * qq + i8;
    int tid = threadIdx.x;
    if (tid < NPB) scnt[tid] = 0;
    __syncthreads();

    int sub = tid >> 1, l = tid & 1;      // 500 sub-runs, 2 lanes each
    int sc = 0; unsigned int base = 0;
    if (sub < NBLK_A) {
        sc   = cnts[b * NBLK_A + sub];
        base = (unsigned int)sub * BINSTRIDE
             + (unsigned int)offs[b * NBLK_A + sub];
    }
    int j0 = l ? (sc >> 1) : 0;           // contiguous half per lane
    int j1 = l ? sc : (sc >> 1);

    // pass 1: 3 unconditional uint4 loads fill the cache; predicated counts
    unsigned int ev[12];
    {
        const uint4* vp = (const uint4*)(binned + base + j0);   // 4B-aligned
        uint4 v0 = vp[0], v1 = vp[1], v2 = vp[2];
        ev[0]=v0.x; ev[1]=v0.y; ev[2]=v0.z;  ev[3]=v0.w;
        ev[4]=v1.x; ev[5]=v1.y; ev[6]=v1.z;  ev[7]=v1.w;
        ev[8]=v2.x; ev[9]=v2.y; ev[10]=v2.z; ev[11]=v2.w;
    }
    #pragma unroll
    for (int u = 0; u < 12; u++)
        if (j0 + u < j1) atomicAdd(&scnt[ev[u] >> 17], 1);
    for (int j = j0 + 12; j < j1; j++)
        atomicAdd(&scnt[binned[base + j] >> 17], 1);
    __syncthreads();

    // pass 2: exclusive scan of 256 counts by wave 0 (shuffle scan)
    if (tid < 64) {
        int i0 = tid * 4;
        int c0 = scnt[i0], c1 = scnt[i0 + 1], c2 = scnt[i0 + 2], c3 = scnt[i0 + 3];
        int s = c0 + c1 + c2 + c3;
        int t = s;
        #pragma unroll
        for (int off = 1; off < 64; off <<= 1) {
            int u = __shfl_up(t, off, 64);
            if (tid >= off) t += u;
        }
        int ex = t - s;
        soff[i0]     = ex;
        soff[i0 + 1] = ex + c0;
        soff[i0 + 2] = ex + c0 + c1;
        soff[i0 + 3] = ex + c0 + c1 + c2;
    }
    __syncthreads();

    // pass 3: scatter into node-sorted sedge from the register cache
    #pragma unroll
    for (int u = 0; u < 12; u++) {
        if (j0 + u < j1) {
            unsigned int p = ev[u];
            int pos = atomicAdd(&soff[p >> 17], 1);
            sedge[pos] = p & 0x1FFFFu;
        }
    }
    for (int j = j0 + 12; j < j1; j++) {
        unsigned int p = binned[base + j];
        int pos = atomicAdd(&soff[p >> 17], 1);
        sedge[pos] = p & 0x1FFFFu;
    }
    __syncthreads();

    // pass 4: accumulate in f16 (v_pk_add_f16), 2 lanes/node, 16B gathers
    if (tid < 2 * NPB) {
        int nl = tid >> 1, q = tid & 1;
        int c  = scnt[nl];
        int s0 = soff[nl] - c;                 // soff advanced to row end
        __half2 z = __floats2half2_rn(0.f, 0.f);
        __half2 ah0 = z, ah1 = z, ah2 = z, ah3 = z;
        #pragma unroll 2
        for (int k = 0; k < c; k++) {
            int col = (int)sedge[s0 + k];      // broadcast within pair
            uint4 raw = ((const uint4*)(xcon + (size_t)col * 16))[q];
            ah0 = __hadd2(ah0, *(const __half2*)&raw.x);
            ah1 = __hadd2(ah1, *(const __half2*)&raw.y);
            ah2 = __hadd2(ah2, *(const __half2*)&raw.z);
            ah3 = __hadd2(ah3, *(const __half2*)&raw.w);
        }
        int n = b * NPB + nl;
        if (n < N_NODES) {
            float inv = 1.0f / (float)max(c, 1);
            float2 f0 = __half22float2(ah0);
            float2 f1 = __half22float2(ah1);
            float2 f2 = __half22float2(ah2);
            float2 f3 = __half22float2(ah3);
            __half2 h0 = __floats2half2_rn(f0.x * inv, f0.y * inv);
            __half2 h1 = __floats2half2_rn(f1.x * inv, f1.y * inv);
            __half2 h2 = __floats2half2_rn(f2.x * inv, f2.y * inv);
            __half2 h3 = __floats2half2_rn(f3.x * inv, f3.y * inv);
            uint4 st;
            st.x = *(unsigned int*)&h0; st.y = *(unsigned int*)&h1;
            st.z = *(unsigned int*)&h2; st.w = *(unsigned int*)&h3;
            *(uint4*)(agg + (size_t)n * 16 + q * 8) = st;   // 16B/lane
        }
    }
}

// ---------------------------------------------------------------------------
// C. MLP (R18-verified fdot2 path, byte-identical). Phase A: radial f32 FMA
//    + conical fdot2 on agg's native half2; phase B: H2 half2 via fdot2
//    against f16 W2^T; f32 accumulation. 8 waves / 64-node tile,
//    wave-uniform weight rows on the scalar pipe.
// ---------------------------------------------------------------------------
__global__ __launch_bounds__(512, 4) void mlp_kernel(
    const float* __restrict__ x, const __half* __restrict__ agg,
    const float* __restrict__ W1tr, const __half* __restrict__ W1th,
    const float* __restrict__ b1,
    const __half* __restrict__ W2th, const float* __restrict__ b2,
    float* __restrict__ out, int N) {
    __shared__ __half2 H2[64 * 64];   // [kp][node], 16 KB
    int tid  = threadIdx.x;
    int lane = tid & 63;
    int ws   = __builtin_amdgcn_readfirstlane(tid >> 6);
    int n    = blockIdx.x * 64 + lane;
    int nc   = min(n, N - 1);

    float combr[16];
    const float4* xr = (const float4*)(x + (size_t)nc * 32);
    #pragma unroll
    for (int c = 0; c < 4; c++) {
        float4 v = xr[c];
        combr[c*4+0] = v.x; combr[c*4+1] = v.y;
        combr[c*4+2] = v.z; combr[c*4+3] = v.w;
    }
    __half2 aggh[8];
    const __half2* ar = (const __half2*)(agg + (size_t)nc * 16);
    #pragma unroll
    for (int c = 0; c < 8; c++) aggh[c] = ar[c];

    #pragma unroll
    for (int i = 0; i < 16; i += 2) {
        int k0 = ws * 16 + i;
        const float*   w1a  = W1tr + k0 * 16;
        const float*   w1b  = w1a + 16;
        const __half2* w1ha = (const __half2*)(W1th + k0 * 16);
        const __half2* w1hb = w1ha + 8;
        float ha = b1[k0], hb = b1[k0 + 1];
        #pragma unroll
        for (int c = 0; c < 16; c++) {
            ha = fmaf(combr[c], w1a[c], ha);
            hb = fmaf(combr[c], w1b[c], hb);
        }
        #pragma unroll
        for (int p = 0; p < 8; p++) {
            ha = fdot2(aggh[p], w1ha[p], ha);
            hb = fdot2(aggh[p], w1hb[p], hb);
        }
        ha = fmaxf(ha, 0.f); hb = fmaxf(hb, 0.f);
        H2[(k0 >> 1) * 64 + lane] = __floats2half2_rn(ha, hb);
    }
    __syncthreads();

    int o0 = ws * 4;
    const __half2* w20 = (const __half2*)(W2th + (o0 + 0) * 128);
    const __half2* w21 = (const __half2*)(W2th + (o0 + 1) * 128);
    const __half2* w22 = (const __half2*)(W2th + (o0 + 2) * 128);
    const __half2* w23 = (const __half2*)(W2th + (o0 + 3) * 128);
    float acc0 = b2[o0+0], acc1 = b2[o0+1], acc2 = b2[o0+2], acc3 = b2[o0+3];
    #pragma unroll 8
    for (int kp = 0; kp < 64; kp++) {
        __half2 hq = H2[kp * 64 + lane];
        acc0 = fdot2(hq, w20[kp], acc0);
        acc1 = fdot2(hq, w21[kp], acc1);
        acc2 = fdot2(hq, w22[kp], acc2);
        acc3 = fdot2(hq, w23[kp], acc3);
    }
    if (n < N) {
        float* op = out + (size_t)n * 32 + o0;
        op[0] = acc0; op[1] = acc1; op[2] = acc2; op[3] = acc3;
    }
}

extern "C" void kernel_launch(void* const* d_in, const int* in_sizes, int n_in,
                              void* d_out, int out_size, void* d_ws, size_t ws_size,
                              hipStream_t stream) {
    const float* x   = (const float*)d_in[0];
    const int*   idx = (const int*)d_in[1];
    const float* W1  = (const float*)d_in[2];
    const float* b1  = (const float*)d_in[3];
    const float* W2  = (const float*)d_in[4];
    const float* b2  = (const float*)d_in[5];
    float* out = (float*)d_out;

    const int E = in_sizes[1] / 2;     // 1,600,000
    const int total = 2 * E;           // 3,200,000

    // ws layout (~21 MB):
    //   agg 3.2MB | xcon 3.2MB | W1tr 8KB | W1th 4KB | W2th 8KB |
    //   cnts 782KB | offs 782KB | binned 500*6400*4 = 12.8MB
    char* base = (char*)d_ws;
    __half*       agg    = (__half*)base;
    __half*       xcon   = (__half*)(base + 3203072);
    float*        W1tr   = (float*)(base + 6406144);
    __half*       W1th   = (__half*)(base + 6414336);
    __half*       W2th   = (__half*)(base + 6418432);
    int*          cnts   = (int*)(base + 6426624);
    int*          offs   = (int*)(base + 7208960);
    unsigned int* binned = (unsigned int*)(base + 7991296);

    int pack_blocks = (N_NODES * 4 + BTHR - 1) / BTHR;   // 782
    binfuse_kernel<<<NBLK_A + 1 + pack_blocks, BTHR, 0, stream>>>(
        idx, x, (__half2*)xcon, W1, W2, W1tr, W1th, W2th,
        binned, cnts, offs, total, E);
    agg_kernel<<<NBKT, 1024, 0, stream>>>(xcon, cnts, offs, binned, agg);
    mlp_kernel<<<(N_NODES + 63) / 64, 512, 0, stream>>>(
        x, agg, W1tr, W1th, b1, W2th, b2, out, N_NODES);
}